// Round 1
// baseline (3407.126 us; speedup 1.0000x reference)
//
#include <hip/hip_runtime.h>

#define GRIDSZ 128
#define NUM_CELLS (GRIDSZ * GRIDSZ * GRIDSZ)
#define DFEAT 8
#define NPTS 1000000
#define INV_CELL 128.0f

// ---------------- P2G: scatter-add contributions ----------------
__global__ __launch_bounds__(256) void p2g_kernel(
    const float* __restrict__ pos,     // [N,3]
    const float* __restrict__ feat,    // [N,8]
    float* __restrict__ grid)          // [128^3, 8]
{
    int n = blockIdx.x * blockDim.x + threadIdx.x;
    if (n >= NPTS) return;

    float px = pos[n * 3 + 0] * INV_CELL;
    float py = pos[n * 3 + 1] * INV_CELL;
    float pz = pos[n * 3 + 2] * INV_CELL;
    int bx = (int)floorf(px), by = (int)floorf(py), bz = (int)floorf(pz);
    float fx = px - (float)bx, fy = py - (float)by, fz = pz - (float)bz;

    // vector-load the 8 features (32B, aligned)
    const float4* fp = reinterpret_cast<const float4*>(feat + (size_t)n * DFEAT);
    float4 f0 = fp[0];
    float4 f1 = fp[1];
    float f[8] = {f0.x, f0.y, f0.z, f0.w, f1.x, f1.y, f1.z, f1.w};

    float wx[2] = {1.0f - fx, fx};
    float wy[2] = {1.0f - fy, fy};
    float wz[2] = {1.0f - fz, fz};

#pragma unroll
    for (int o = 0; o < 8; ++o) {
        int ox = (o >> 2) & 1, oy = (o >> 1) & 1, oz = o & 1;
        float w = wx[ox] * wy[oy] * wz[oz];
        int cx = (bx + ox) & (GRIDSZ - 1);
        int cy = (by + oy) & (GRIDSZ - 1);
        int cz = (bz + oz) & (GRIDSZ - 1);
        int hid = (cx * GRIDSZ + cy) * GRIDSZ + cz;
        float* g = grid + (size_t)hid * DFEAT;
#pragma unroll
        for (int d = 0; d < DFEAT; ++d) {
            atomicAdd(g + d, w * f[d]);
        }
    }
}

// ---------------- G2P: gather back ----------------
__global__ __launch_bounds__(256) void g2p_kernel(
    const float* __restrict__ pos,     // [N,3]
    const float* __restrict__ grid,    // [128^3, 8]
    float* __restrict__ out)           // [N,8]
{
    int n = blockIdx.x * blockDim.x + threadIdx.x;
    if (n >= NPTS) return;

    float px = pos[n * 3 + 0] * INV_CELL;
    float py = pos[n * 3 + 1] * INV_CELL;
    float pz = pos[n * 3 + 2] * INV_CELL;
    int bx = (int)floorf(px), by = (int)floorf(py), bz = (int)floorf(pz);
    float fx = px - (float)bx, fy = py - (float)by, fz = pz - (float)bz;

    float wx[2] = {1.0f - fx, fx};
    float wy[2] = {1.0f - fy, fy};
    float wz[2] = {1.0f - fz, fz};

    float4 acc0 = {0.f, 0.f, 0.f, 0.f};
    float4 acc1 = {0.f, 0.f, 0.f, 0.f};

#pragma unroll
    for (int o = 0; o < 8; ++o) {
        int ox = (o >> 2) & 1, oy = (o >> 1) & 1, oz = o & 1;
        float w = wx[ox] * wy[oy] * wz[oz];
        int cx = (bx + ox) & (GRIDSZ - 1);
        int cy = (by + oy) & (GRIDSZ - 1);
        int cz = (bz + oz) & (GRIDSZ - 1);
        int hid = (cx * GRIDSZ + cy) * GRIDSZ + cz;
        const float4* g = reinterpret_cast<const float4*>(grid + (size_t)hid * DFEAT);
        float4 g0 = g[0];
        float4 g1 = g[1];
        acc0.x += w * g0.x; acc0.y += w * g0.y; acc0.z += w * g0.z; acc0.w += w * g0.w;
        acc1.x += w * g1.x; acc1.y += w * g1.y; acc1.z += w * g1.z; acc1.w += w * g1.w;
    }

    float4* op = reinterpret_cast<float4*>(out + (size_t)n * DFEAT);
    op[0] = acc0;
    op[1] = acc1;
}

extern "C" void kernel_launch(void* const* d_in, const int* in_sizes, int n_in,
                              void* d_out, int out_size, void* d_ws, size_t ws_size,
                              hipStream_t stream) {
    const float* pos = (const float*)d_in[0];   // [N,3] f32
    const float* feat = (const float*)d_in[1];  // [N,8] f32
    float* out = (float*)d_out;                 // [N,8] f32
    float* grid = (float*)d_ws;                 // [128^3, 8] f32 = 64 MiB

    size_t grid_bytes = (size_t)NUM_CELLS * DFEAT * sizeof(float);
    hipMemsetAsync(d_ws, 0, grid_bytes, stream);

    int block = 256;
    int nblocks = (NPTS + block - 1) / block;
    p2g_kernel<<<nblocks, block, 0, stream>>>(pos, feat, grid);
    g2p_kernel<<<nblocks, block, 0, stream>>>(pos, grid, out);
}

// Round 2
// 572.330 us; speedup vs baseline: 5.9531x; 5.9531x over previous
//
#include <hip/hip_runtime.h>

#define GRIDSZ 128
#define GMASK 127
#define NUM_CELLS (GRIDSZ * GRIDSZ * GRIDSZ)   // 2,097,152
#define DFEAT 8
#define NPTS 1000000
#define INV_CELL 128.0f

#define SCAN_BLK 256
#define SCAN_ELEMS 8
#define SCAN_TILE (SCAN_BLK * SCAN_ELEMS)       // 2048
#define NSCAN_BLOCKS (NUM_CELLS / SCAN_TILE)    // 1024

// ---------------- histogram: count points per cell, remember each point's cell ----------------
__global__ __launch_bounds__(256) void hist_kernel(
    const float* __restrict__ pos,
    int* __restrict__ counts,
    int* __restrict__ hid_out)
{
    int n = blockIdx.x * blockDim.x + threadIdx.x;
    if (n >= NPTS) return;
    float px = pos[n * 3 + 0] * INV_CELL;
    float py = pos[n * 3 + 1] * INV_CELL;
    float pz = pos[n * 3 + 2] * INV_CELL;
    int bx = (int)floorf(px), by = (int)floorf(py), bz = (int)floorf(pz);
    int h = ((bx & GMASK) << 14) | ((by & GMASK) << 7) | (bz & GMASK);
    hid_out[n] = h;
    atomicAdd(&counts[h], 1);
}

// ---------------- scan: exclusive prefix over 2M cell counts (3 kernels) ----------------
__global__ __launch_bounds__(SCAN_BLK) void scan_a(
    const int* __restrict__ counts,
    int* __restrict__ offsets,
    int* __restrict__ partial)
{
    __shared__ int lds[SCAN_BLK];
    int t = threadIdx.x;
    int base = blockIdx.x * SCAN_TILE + t * SCAN_ELEMS;
    int v[SCAN_ELEMS];
    int s = 0;
#pragma unroll
    for (int i = 0; i < SCAN_ELEMS; ++i) { v[i] = counts[base + i]; s += v[i]; }
    lds[t] = s;
    __syncthreads();
    int incl = s;
    for (int off = 1; off < SCAN_BLK; off <<= 1) {
        int tmp = (t >= off) ? lds[t - off] : 0;
        __syncthreads();
        incl += tmp;
        lds[t] = incl;
        __syncthreads();
    }
    int excl = incl - s;
#pragma unroll
    for (int i = 0; i < SCAN_ELEMS; ++i) { offsets[base + i] = excl; excl += v[i]; }
    if (t == SCAN_BLK - 1) partial[blockIdx.x] = incl;
}

__global__ __launch_bounds__(1024) void scan_b(int* __restrict__ partial)
{
    __shared__ int lds[NSCAN_BLOCKS];
    int t = threadIdx.x;
    int p = partial[t];
    lds[t] = p;
    __syncthreads();
    int incl = p;
    for (int off = 1; off < NSCAN_BLOCKS; off <<= 1) {
        int tmp = (t >= off) ? lds[t - off] : 0;
        __syncthreads();
        incl += tmp;
        lds[t] = incl;
        __syncthreads();
    }
    partial[t] = incl - p;   // exclusive
}

__global__ __launch_bounds__(256) void scan_c(
    int* __restrict__ offsets, const int* __restrict__ partial)
{
    int i = blockIdx.x * blockDim.x + threadIdx.x;   // exactly NUM_CELLS threads
    offsets[i] += partial[i / SCAN_TILE];
}

// ---------------- scatter: place point indices in cell-sorted order ----------------
// offsets is MUTATED: afterwards offsets[c] == end of cell c's range
// (start of cell c == offsets[c-1], or 0 for c==0).
__global__ __launch_bounds__(256) void scatter_kernel(
    const int* __restrict__ hid,
    int* __restrict__ offsets,
    int* __restrict__ sortedIdx)
{
    int n = blockIdx.x * blockDim.x + threadIdx.x;
    if (n >= NPTS) return;
    int c = hid[n];
    int slot = atomicAdd(&offsets[c], 1);
    sortedIdx[slot] = n;
}

// ---------------- node gather: P2G without atomics ----------------
__global__ __launch_bounds__(256) void node_gather_kernel(
    const int* __restrict__ offsets_end,   // post-scatter offsets (end of each cell)
    const int* __restrict__ sortedIdx,
    const float* __restrict__ pos,
    const float* __restrict__ feat,
    float* __restrict__ grid)
{
    int n = blockIdx.x * blockDim.x + threadIdx.x;   // exactly NUM_CELLS threads
    int nz = n & GMASK, ny = (n >> 7) & GMASK, nx = n >> 14;
    float4 a0 = {0.f, 0.f, 0.f, 0.f};
    float4 a1 = {0.f, 0.f, 0.f, 0.f};
#pragma unroll
    for (int o = 0; o < 8; ++o) {
        int ox = (o >> 2) & 1, oy = (o >> 1) & 1, oz = o & 1;
        int bx = (nx - ox) & GMASK, by = (ny - oy) & GMASK, bz = (nz - oz) & GMASK;
        int c = (bx << 14) | (by << 7) | bz;
        int st = (c == 0) ? 0 : offsets_end[c - 1];
        int en = offsets_end[c];
        for (int j = st; j < en; ++j) {
            int idx = sortedIdx[j];
            float fx = pos[idx * 3 + 0] * INV_CELL - (float)bx;
            float fy = pos[idx * 3 + 1] * INV_CELL - (float)by;
            float fz = pos[idx * 3 + 2] * INV_CELL - (float)bz;
            float w = (ox ? fx : 1.f - fx) * (oy ? fy : 1.f - fy) * (oz ? fz : 1.f - fz);
            const float4* fp = reinterpret_cast<const float4*>(feat + (size_t)idx * DFEAT);
            float4 f0 = fp[0];
            float4 f1 = fp[1];
            a0.x += w * f0.x; a0.y += w * f0.y; a0.z += w * f0.z; a0.w += w * f0.w;
            a1.x += w * f1.x; a1.y += w * f1.y; a1.z += w * f1.z; a1.w += w * f1.w;
        }
    }
    float4* gp = reinterpret_cast<float4*>(grid + (size_t)n * DFEAT);
    gp[0] = a0;
    gp[1] = a1;
}

// ---------------- G2P: gather back to points ----------------
__global__ __launch_bounds__(256) void g2p_kernel(
    const float* __restrict__ pos,
    const float* __restrict__ grid,
    float* __restrict__ out)
{
    int n = blockIdx.x * blockDim.x + threadIdx.x;
    if (n >= NPTS) return;
    float px = pos[n * 3 + 0] * INV_CELL;
    float py = pos[n * 3 + 1] * INV_CELL;
    float pz = pos[n * 3 + 2] * INV_CELL;
    int bx = (int)floorf(px), by = (int)floorf(py), bz = (int)floorf(pz);
    float fx = px - (float)bx, fy = py - (float)by, fz = pz - (float)bz;

    float wx[2] = {1.0f - fx, fx};
    float wy[2] = {1.0f - fy, fy};
    float wz[2] = {1.0f - fz, fz};

    float4 acc0 = {0.f, 0.f, 0.f, 0.f};
    float4 acc1 = {0.f, 0.f, 0.f, 0.f};
#pragma unroll
    for (int o = 0; o < 8; ++o) {
        int ox = (o >> 2) & 1, oy = (o >> 1) & 1, oz = o & 1;
        float w = wx[ox] * wy[oy] * wz[oz];
        int cx = (bx + ox) & GMASK;
        int cy = (by + oy) & GMASK;
        int cz = (bz + oz) & GMASK;
        int hid = (cx << 14) | (cy << 7) | cz;
        const float4* g = reinterpret_cast<const float4*>(grid + (size_t)hid * DFEAT);
        float4 g0 = g[0];
        float4 g1 = g[1];
        acc0.x += w * g0.x; acc0.y += w * g0.y; acc0.z += w * g0.z; acc0.w += w * g0.w;
        acc1.x += w * g1.x; acc1.y += w * g1.y; acc1.z += w * g1.z; acc1.w += w * g1.w;
    }
    float4* op = reinterpret_cast<float4*>(out + (size_t)n * DFEAT);
    op[0] = acc0;
    op[1] = acc1;
}

// ---------------- fallback (atomic) P2G, used only if ws too small ----------------
__global__ __launch_bounds__(256) void p2g_atomic_kernel(
    const float* __restrict__ pos,
    const float* __restrict__ feat,
    float* __restrict__ grid)
{
    int n = blockIdx.x * blockDim.x + threadIdx.x;
    if (n >= NPTS) return;
    float px = pos[n * 3 + 0] * INV_CELL;
    float py = pos[n * 3 + 1] * INV_CELL;
    float pz = pos[n * 3 + 2] * INV_CELL;
    int bx = (int)floorf(px), by = (int)floorf(py), bz = (int)floorf(pz);
    float fx = px - (float)bx, fy = py - (float)by, fz = pz - (float)bz;
    const float4* fp = reinterpret_cast<const float4*>(feat + (size_t)n * DFEAT);
    float4 f0 = fp[0];
    float4 f1 = fp[1];
    float f[8] = {f0.x, f0.y, f0.z, f0.w, f1.x, f1.y, f1.z, f1.w};
    float wx[2] = {1.0f - fx, fx};
    float wy[2] = {1.0f - fy, fy};
    float wz[2] = {1.0f - fz, fz};
#pragma unroll
    for (int o = 0; o < 8; ++o) {
        int ox = (o >> 2) & 1, oy = (o >> 1) & 1, oz = o & 1;
        float w = wx[ox] * wy[oy] * wz[oz];
        int cx = (bx + ox) & GMASK, cy = (by + oy) & GMASK, cz = (bz + oz) & GMASK;
        int hid = (cx << 14) | (cy << 7) | cz;
        float* g = grid + (size_t)hid * DFEAT;
#pragma unroll
        for (int d = 0; d < DFEAT; ++d) atomicAdd(g + d, w * f[d]);
    }
}

extern "C" void kernel_launch(void* const* d_in, const int* in_sizes, int n_in,
                              void* d_out, int out_size, void* d_ws, size_t ws_size,
                              hipStream_t stream) {
    const float* pos  = (const float*)d_in[0];   // [N,3] f32
    const float* feat = (const float*)d_in[1];   // [N,8] f32
    float* out = (float*)d_out;                  // [N,8] f32

    // workspace layout
    char* ws = (char*)d_ws;
    size_t grid_bytes    = (size_t)NUM_CELLS * DFEAT * sizeof(float);  // 64 MiB
    size_t counts_bytes  = (size_t)NUM_CELLS * sizeof(int);            // 8 MiB
    size_t offsets_bytes = (size_t)NUM_CELLS * sizeof(int);            // 8 MiB
    size_t sidx_bytes    = (size_t)NPTS * sizeof(int);                 // 4 MiB
    size_t hid_bytes     = (size_t)NPTS * sizeof(int);                 // 4 MiB
    size_t partial_bytes = (size_t)NSCAN_BLOCKS * sizeof(int);         // 4 KiB

    float* grid    = (float*)ws;
    int* counts    = (int*)(ws + grid_bytes);
    int* offsets   = (int*)(ws + grid_bytes + counts_bytes);
    int* sortedIdx = (int*)(ws + grid_bytes + counts_bytes + offsets_bytes);
    int* hid       = (int*)(ws + grid_bytes + counts_bytes + offsets_bytes + sidx_bytes);
    int* partial   = (int*)(ws + grid_bytes + counts_bytes + offsets_bytes + sidx_bytes + hid_bytes);
    size_t needed = grid_bytes + counts_bytes + offsets_bytes + sidx_bytes + hid_bytes + partial_bytes;

    int block = 256;
    int nblk_pts = (NPTS + block - 1) / block;
    int nblk_cells = NUM_CELLS / block;   // 8192

    if (ws_size >= needed) {
        // fast path: counting-sort + gather (no float atomics)
        hipMemsetAsync(counts, 0, counts_bytes, stream);
        hist_kernel<<<nblk_pts, block, 0, stream>>>(pos, counts, hid);
        scan_a<<<NSCAN_BLOCKS, SCAN_BLK, 0, stream>>>(counts, offsets, partial);
        scan_b<<<1, NSCAN_BLOCKS, 0, stream>>>(partial);
        scan_c<<<nblk_cells, block, 0, stream>>>(offsets, partial);
        scatter_kernel<<<nblk_pts, block, 0, stream>>>(hid, offsets, sortedIdx);
        node_gather_kernel<<<nblk_cells, block, 0, stream>>>(offsets, sortedIdx, pos, feat, grid);
        g2p_kernel<<<nblk_pts, block, 0, stream>>>(pos, grid, out);
    } else {
        // fallback: atomic scatter
        hipMemsetAsync(grid, 0, grid_bytes, stream);
        p2g_atomic_kernel<<<nblk_pts, block, 0, stream>>>(pos, feat, grid);
        g2p_kernel<<<nblk_pts, block, 0, stream>>>(pos, grid, out);
    }
}

// Round 3
// 360.424 us; speedup vs baseline: 9.4531x; 1.5879x over previous
//
#include <hip/hip_runtime.h>

#define GRIDSZ 128
#define GMASK 127
#define NUM_CELLS (GRIDSZ * GRIDSZ * GRIDSZ)   // 2,097,152
#define DFEAT 8
#define NPTS 1000000
#define INV_CELL 128.0f

#define SCAN_BLK 256
#define SCAN_ELEMS 8
#define SCAN_TILE (SCAN_BLK * SCAN_ELEMS)       // 2048
#define NSCAN_BLOCKS (NUM_CELLS / SCAN_TILE)    // 1024

// ---------------- histogram: count points per cell ----------------
__global__ __launch_bounds__(256) void hist_kernel(
    const float* __restrict__ pos,
    int* __restrict__ counts)
{
    int n = blockIdx.x * blockDim.x + threadIdx.x;
    if (n >= NPTS) return;
    float px = pos[n * 3 + 0] * INV_CELL;
    float py = pos[n * 3 + 1] * INV_CELL;
    float pz = pos[n * 3 + 2] * INV_CELL;
    int bx = (int)floorf(px), by = (int)floorf(py), bz = (int)floorf(pz);
    int h = ((bx & GMASK) << 14) | ((by & GMASK) << 7) | (bz & GMASK);
    atomicAdd(&counts[h], 1);
}

// ---------------- scan: exclusive prefix over 2M cell counts, IN PLACE ----------------
__global__ __launch_bounds__(SCAN_BLK) void scan_a(
    int* __restrict__ data,          // counts in, exclusive-scanned (per tile) out
    int* __restrict__ partial)
{
    __shared__ int lds[SCAN_BLK];
    int t = threadIdx.x;
    int base = blockIdx.x * SCAN_TILE + t * SCAN_ELEMS;
    int v[SCAN_ELEMS];
    int s = 0;
#pragma unroll
    for (int i = 0; i < SCAN_ELEMS; ++i) { v[i] = data[base + i]; s += v[i]; }
    lds[t] = s;
    __syncthreads();
    int incl = s;
    for (int off = 1; off < SCAN_BLK; off <<= 1) {
        int tmp = (t >= off) ? lds[t - off] : 0;
        __syncthreads();
        incl += tmp;
        lds[t] = incl;
        __syncthreads();
    }
    int excl = incl - s;
#pragma unroll
    for (int i = 0; i < SCAN_ELEMS; ++i) { data[base + i] = excl; excl += v[i]; }
    if (t == SCAN_BLK - 1) partial[blockIdx.x] = incl;
}

__global__ __launch_bounds__(1024) void scan_b(int* __restrict__ partial)
{
    __shared__ int lds[NSCAN_BLOCKS];
    int t = threadIdx.x;
    int p = partial[t];
    lds[t] = p;
    __syncthreads();
    int incl = p;
    for (int off = 1; off < NSCAN_BLOCKS; off <<= 1) {
        int tmp = (t >= off) ? lds[t - off] : 0;
        __syncthreads();
        incl += tmp;
        lds[t] = incl;
        __syncthreads();
    }
    partial[t] = incl - p;   // exclusive
}

__global__ __launch_bounds__(256) void scan_c(
    int* __restrict__ offsets, const int* __restrict__ partial)
{
    int i = blockIdx.x * blockDim.x + threadIdx.x;   // exactly NUM_CELLS threads
    offsets[i] += partial[i / SCAN_TILE];
}

// ---------------- scatter+reorder: place frac coords & features in cell-sorted order ----
// offsets is MUTATED: afterwards offsets[c] == end of cell c's range.
__global__ __launch_bounds__(256) void scatter_kernel(
    const float* __restrict__ pos,
    const float* __restrict__ feat,
    int* __restrict__ offsets,
    float4* __restrict__ frac_s,     // [N] (fx,fy,fz,-)
    float4* __restrict__ feat_s)     // [N*2]
{
    int n = blockIdx.x * blockDim.x + threadIdx.x;
    if (n >= NPTS) return;
    float px = pos[n * 3 + 0] * INV_CELL;
    float py = pos[n * 3 + 1] * INV_CELL;
    float pz = pos[n * 3 + 2] * INV_CELL;
    int bx = (int)floorf(px), by = (int)floorf(py), bz = (int)floorf(pz);
    float fx = px - (float)bx, fy = py - (float)by, fz = pz - (float)bz;
    int c = ((bx & GMASK) << 14) | ((by & GMASK) << 7) | (bz & GMASK);
    int slot = atomicAdd(&offsets[c], 1);

    const float4* fp = reinterpret_cast<const float4*>(feat + (size_t)n * DFEAT);
    float4 f0 = fp[0];
    float4 f1 = fp[1];
    frac_s[slot] = make_float4(fx, fy, fz, 0.f);
    feat_s[(size_t)slot * 2 + 0] = f0;
    feat_s[(size_t)slot * 2 + 1] = f1;
}

// ---------------- node gather: P2G without atomics, sorted contiguous reads ----------
__global__ __launch_bounds__(256) void node_gather_kernel(
    const int* __restrict__ offsets_end,   // post-scatter offsets (end of each cell)
    const float4* __restrict__ frac_s,
    const float4* __restrict__ feat_s,
    float* __restrict__ grid)
{
    int n = blockIdx.x * blockDim.x + threadIdx.x;   // exactly NUM_CELLS threads
    int nz = n & GMASK, ny = (n >> 7) & GMASK, nx = n >> 14;
    float4 a0 = {0.f, 0.f, 0.f, 0.f};
    float4 a1 = {0.f, 0.f, 0.f, 0.f};
#pragma unroll
    for (int o = 0; o < 8; ++o) {
        int ox = (o >> 2) & 1, oy = (o >> 1) & 1, oz = o & 1;
        int bx = (nx - ox) & GMASK, by = (ny - oy) & GMASK, bz = (nz - oz) & GMASK;
        int c = (bx << 14) | (by << 7) | bz;
        int st = (c == 0) ? 0 : offsets_end[c - 1];
        int en = offsets_end[c];
        for (int j = st; j < en; ++j) {
            float4 fr = frac_s[j];
            float w = (ox ? fr.x : 1.f - fr.x)
                    * (oy ? fr.y : 1.f - fr.y)
                    * (oz ? fr.z : 1.f - fr.z);
            float4 f0 = feat_s[(size_t)j * 2 + 0];
            float4 f1 = feat_s[(size_t)j * 2 + 1];
            a0.x += w * f0.x; a0.y += w * f0.y; a0.z += w * f0.z; a0.w += w * f0.w;
            a1.x += w * f1.x; a1.y += w * f1.y; a1.z += w * f1.z; a1.w += w * f1.w;
        }
    }
    float4* gp = reinterpret_cast<float4*>(grid + (size_t)n * DFEAT);
    gp[0] = a0;
    gp[1] = a1;
}

// ---------------- G2P: gather back to points ----------------
__global__ __launch_bounds__(256) void g2p_kernel(
    const float* __restrict__ pos,
    const float* __restrict__ grid,
    float* __restrict__ out)
{
    int n = blockIdx.x * blockDim.x + threadIdx.x;
    if (n >= NPTS) return;
    float px = pos[n * 3 + 0] * INV_CELL;
    float py = pos[n * 3 + 1] * INV_CELL;
    float pz = pos[n * 3 + 2] * INV_CELL;
    int bx = (int)floorf(px), by = (int)floorf(py), bz = (int)floorf(pz);
    float fx = px - (float)bx, fy = py - (float)by, fz = pz - (float)bz;

    float wx[2] = {1.0f - fx, fx};
    float wy[2] = {1.0f - fy, fy};
    float wz[2] = {1.0f - fz, fz};

    float4 acc0 = {0.f, 0.f, 0.f, 0.f};
    float4 acc1 = {0.f, 0.f, 0.f, 0.f};
#pragma unroll
    for (int o = 0; o < 8; ++o) {
        int ox = (o >> 2) & 1, oy = (o >> 1) & 1, oz = o & 1;
        float w = wx[ox] * wy[oy] * wz[oz];
        int cx = (bx + ox) & GMASK;
        int cy = (by + oy) & GMASK;
        int cz = (bz + oz) & GMASK;
        int hid = (cx << 14) | (cy << 7) | cz;
        const float4* g = reinterpret_cast<const float4*>(grid + (size_t)hid * DFEAT);
        float4 g0 = g[0];
        float4 g1 = g[1];
        acc0.x += w * g0.x; acc0.y += w * g0.y; acc0.z += w * g0.z; acc0.w += w * g0.w;
        acc1.x += w * g1.x; acc1.y += w * g1.y; acc1.z += w * g1.z; acc1.w += w * g1.w;
    }
    float4* op = reinterpret_cast<float4*>(out + (size_t)n * DFEAT);
    op[0] = acc0;
    op[1] = acc1;
}

// ---------------- fallback (atomic) P2G, used only if ws too small ----------------
__global__ __launch_bounds__(256) void p2g_atomic_kernel(
    const float* __restrict__ pos,
    const float* __restrict__ feat,
    float* __restrict__ grid)
{
    int n = blockIdx.x * blockDim.x + threadIdx.x;
    if (n >= NPTS) return;
    float px = pos[n * 3 + 0] * INV_CELL;
    float py = pos[n * 3 + 1] * INV_CELL;
    float pz = pos[n * 3 + 2] * INV_CELL;
    int bx = (int)floorf(px), by = (int)floorf(py), bz = (int)floorf(pz);
    float fx = px - (float)bx, fy = py - (float)by, fz = pz - (float)bz;
    const float4* fp = reinterpret_cast<const float4*>(feat + (size_t)n * DFEAT);
    float4 f0 = fp[0];
    float4 f1 = fp[1];
    float f[8] = {f0.x, f0.y, f0.z, f0.w, f1.x, f1.y, f1.z, f1.w};
    float wx[2] = {1.0f - fx, fx};
    float wy[2] = {1.0f - fy, fy};
    float wz[2] = {1.0f - fz, fz};
#pragma unroll
    for (int o = 0; o < 8; ++o) {
        int ox = (o >> 2) & 1, oy = (o >> 1) & 1, oz = o & 1;
        float w = wx[ox] * wy[oy] * wz[oz];
        int cx = (bx + ox) & GMASK, cy = (by + oy) & GMASK, cz = (bz + oz) & GMASK;
        int hid = (cx << 14) | (cy << 7) | cz;
        float* g = grid + (size_t)hid * DFEAT;
#pragma unroll
        for (int d = 0; d < DFEAT; ++d) atomicAdd(g + d, w * f[d]);
    }
}

extern "C" void kernel_launch(void* const* d_in, const int* in_sizes, int n_in,
                              void* d_out, int out_size, void* d_ws, size_t ws_size,
                              hipStream_t stream) {
    const float* pos  = (const float*)d_in[0];   // [N,3] f32
    const float* feat = (const float*)d_in[1];   // [N,8] f32
    float* out = (float*)d_out;                  // [N,8] f32

    // workspace layout
    char* ws = (char*)d_ws;
    size_t grid_bytes    = (size_t)NUM_CELLS * DFEAT * sizeof(float);  // 64 MiB
    size_t offsets_bytes = (size_t)NUM_CELLS * sizeof(int);            // 8 MiB
    size_t frac_bytes    = (size_t)NPTS * sizeof(float4);              // 16 MB
    size_t feats_bytes   = (size_t)NPTS * 2 * sizeof(float4);          // 32 MB
    size_t partial_bytes = (size_t)NSCAN_BLOCKS * sizeof(int);         // 4 KiB

    float* grid     = (float*)ws;
    int* offsets    = (int*)(ws + grid_bytes);
    float4* frac_s  = (float4*)(ws + grid_bytes + offsets_bytes);
    float4* feat_s  = (float4*)(ws + grid_bytes + offsets_bytes + frac_bytes);
    int* partial    = (int*)(ws + grid_bytes + offsets_bytes + frac_bytes + feats_bytes);
    size_t needed = grid_bytes + offsets_bytes + frac_bytes + feats_bytes + partial_bytes;

    int block = 256;
    int nblk_pts = (NPTS + block - 1) / block;
    int nblk_cells = NUM_CELLS / block;   // 8192

    if (ws_size >= needed) {
        // fast path: counting-sort (fused reorder) + node gather (no float atomics)
        hipMemsetAsync(offsets, 0, offsets_bytes, stream);
        hist_kernel<<<nblk_pts, block, 0, stream>>>(pos, offsets);
        scan_a<<<NSCAN_BLOCKS, SCAN_BLK, 0, stream>>>(offsets, partial);
        scan_b<<<1, NSCAN_BLOCKS, 0, stream>>>(partial);
        scan_c<<<nblk_cells, block, 0, stream>>>(offsets, partial);
        scatter_kernel<<<nblk_pts, block, 0, stream>>>(pos, feat, offsets, frac_s, feat_s);
        node_gather_kernel<<<nblk_cells, block, 0, stream>>>(offsets, frac_s, feat_s, grid);
        g2p_kernel<<<nblk_pts, block, 0, stream>>>(pos, grid, out);
    } else {
        // fallback: atomic scatter
        hipMemsetAsync(grid, 0, grid_bytes, stream);
        p2g_atomic_kernel<<<nblk_pts, block, 0, stream>>>(pos, feat, grid);
        g2p_kernel<<<nblk_pts, block, 0, stream>>>(pos, grid, out);
    }
}

// Round 4
// 309.250 us; speedup vs baseline: 11.0174x; 1.1655x over previous
//
#include <hip/hip_runtime.h>

#define GRIDSZ 128
#define GMASK 127
#define NUM_CELLS (GRIDSZ * GRIDSZ * GRIDSZ)   // 2,097,152
#define DFEAT 8
#define NPTS 1000000
#define INV_CELL 128.0f

#define SCAN_BLK 256
#define SCAN_ELEMS 8
#define SCAN_TILE (SCAN_BLK * SCAN_ELEMS)       // 2048
#define NSCAN_BLOCKS (NUM_CELLS / SCAN_TILE)    // 1024

// ---------------- histogram: count points per cell ----------------
__global__ __launch_bounds__(256) void hist_kernel(
    const float* __restrict__ pos,
    int* __restrict__ counts)
{
    int n = blockIdx.x * blockDim.x + threadIdx.x;
    if (n >= NPTS) return;
    float px = pos[n * 3 + 0] * INV_CELL;
    float py = pos[n * 3 + 1] * INV_CELL;
    float pz = pos[n * 3 + 2] * INV_CELL;
    int bx = (int)floorf(px), by = (int)floorf(py), bz = (int)floorf(pz);
    int h = ((bx & GMASK) << 14) | ((by & GMASK) << 7) | (bz & GMASK);
    atomicAdd(&counts[h], 1);
}

// ---------------- scan: exclusive prefix over 2M cell counts, IN PLACE ----------------
__global__ __launch_bounds__(SCAN_BLK) void scan_a(
    int* __restrict__ data,          // counts in, exclusive-scanned (per tile) out
    int* __restrict__ partial)
{
    __shared__ int lds[SCAN_BLK];
    int t = threadIdx.x;
    int base = blockIdx.x * SCAN_TILE + t * SCAN_ELEMS;
    int v[SCAN_ELEMS];
    int s = 0;
#pragma unroll
    for (int i = 0; i < SCAN_ELEMS; ++i) { v[i] = data[base + i]; s += v[i]; }
    lds[t] = s;
    __syncthreads();
    int incl = s;
    for (int off = 1; off < SCAN_BLK; off <<= 1) {
        int tmp = (t >= off) ? lds[t - off] : 0;
        __syncthreads();
        incl += tmp;
        lds[t] = incl;
        __syncthreads();
    }
    int excl = incl - s;
#pragma unroll
    for (int i = 0; i < SCAN_ELEMS; ++i) { data[base + i] = excl; excl += v[i]; }
    if (t == SCAN_BLK - 1) partial[blockIdx.x] = incl;
}

__global__ __launch_bounds__(1024) void scan_b(int* __restrict__ partial)
{
    __shared__ int lds[NSCAN_BLOCKS];
    int t = threadIdx.x;
    int p = partial[t];
    lds[t] = p;
    __syncthreads();
    int incl = p;
    for (int off = 1; off < NSCAN_BLOCKS; off <<= 1) {
        int tmp = (t >= off) ? lds[t - off] : 0;
        __syncthreads();
        incl += tmp;
        lds[t] = incl;
        __syncthreads();
    }
    partial[t] = incl - p;   // exclusive
}

__global__ __launch_bounds__(256) void scan_c(
    int* __restrict__ offsets, const int* __restrict__ partial)
{
    int i = blockIdx.x * blockDim.x + threadIdx.x;   // exactly NUM_CELLS threads
    offsets[i] += partial[i / SCAN_TILE];
}

// ---------------- scatter+reorder: frac/cell, feat, and orig idx into sorted order ----
// offsets is MUTATED: afterwards offsets[c] == end of cell c's range.
__global__ __launch_bounds__(256) void scatter_kernel(
    const float* __restrict__ pos,
    const float* __restrict__ feat,
    int* __restrict__ offsets,
    float4* __restrict__ frac_s,     // [N] (fx,fy,fz, cell-id-as-int-bits)
    float4* __restrict__ feat_s,     // [N*2]
    int* __restrict__ orig_s)        // [N] original point index
{
    int n = blockIdx.x * blockDim.x + threadIdx.x;
    if (n >= NPTS) return;
    float px = pos[n * 3 + 0] * INV_CELL;
    float py = pos[n * 3 + 1] * INV_CELL;
    float pz = pos[n * 3 + 2] * INV_CELL;
    int bx = (int)floorf(px), by = (int)floorf(py), bz = (int)floorf(pz);
    float fx = px - (float)bx, fy = py - (float)by, fz = pz - (float)bz;
    int c = ((bx & GMASK) << 14) | ((by & GMASK) << 7) | (bz & GMASK);
    int slot = atomicAdd(&offsets[c], 1);

    const float4* fp = reinterpret_cast<const float4*>(feat + (size_t)n * DFEAT);
    float4 f0 = fp[0];
    float4 f1 = fp[1];
    frac_s[slot] = make_float4(fx, fy, fz, __int_as_float(c));
    feat_s[(size_t)slot * 2 + 0] = f0;
    feat_s[(size_t)slot * 2 + 1] = f1;
    orig_s[slot] = n;
}

// ---------------- node gather: P2G without atomics, z-merged contiguous ranges ------
__global__ __launch_bounds__(256) void node_gather_kernel(
    const int* __restrict__ offsets_end,   // post-scatter offsets (end of each cell)
    const float4* __restrict__ frac_s,
    const float4* __restrict__ feat_s,
    float* __restrict__ grid)
{
    int n = blockIdx.x * blockDim.x + threadIdx.x;   // exactly NUM_CELLS threads
    int nz = n & GMASK, ny = (n >> 7) & GMASK, nx = n >> 14;
    float4 a0 = {0.f, 0.f, 0.f, 0.f};
    float4 a1 = {0.f, 0.f, 0.f, 0.f};
#pragma unroll
    for (int oxy = 0; oxy < 4; ++oxy) {
        int ox = oxy >> 1, oy = oxy & 1;
        int bx = (nx - ox) & GMASK, by = (ny - oy) & GMASK;
        int cbase = (bx << 14) | (by << 7);
        int c1 = cbase | nz;              // cell at z=nz   (node offset oz=0 -> wz = 1-fz)
        if (nz > 0) {
            int c0 = c1 - 1;              // cell at z=nz-1 (node offset oz=1 -> wz = fz)
            int st0 = (c0 == 0) ? 0 : offsets_end[c0 - 1];
            int en0 = offsets_end[c0];
            int en1 = offsets_end[c1];
            for (int j = st0; j < en1; ++j) {
                float4 fr = frac_s[j];
                float wz = (j < en0) ? fr.z : 1.f - fr.z;
                float w = (ox ? fr.x : 1.f - fr.x) * (oy ? fr.y : 1.f - fr.y) * wz;
                float4 f0 = feat_s[(size_t)j * 2 + 0];
                float4 f1 = feat_s[(size_t)j * 2 + 1];
                a0.x += w * f0.x; a0.y += w * f0.y; a0.z += w * f0.z; a0.w += w * f0.w;
                a1.x += w * f1.x; a1.y += w * f1.y; a1.z += w * f1.z; a1.w += w * f1.w;
            }
        } else {
            // wrap: cell at z=127 (oz=1) and cell at z=0 (oz=0), non-contiguous
            int c0 = cbase | 127;
            int st0 = offsets_end[c0 - 1];
            int en0 = offsets_end[c0];
            for (int j = st0; j < en0; ++j) {
                float4 fr = frac_s[j];
                float w = (ox ? fr.x : 1.f - fr.x) * (oy ? fr.y : 1.f - fr.y) * fr.z;
                float4 f0 = feat_s[(size_t)j * 2 + 0];
                float4 f1 = feat_s[(size_t)j * 2 + 1];
                a0.x += w * f0.x; a0.y += w * f0.y; a0.z += w * f0.z; a0.w += w * f0.w;
                a1.x += w * f1.x; a1.y += w * f1.y; a1.z += w * f1.z; a1.w += w * f1.w;
            }
            int st1 = (c1 == 0) ? 0 : offsets_end[c1 - 1];
            int en1 = offsets_end[c1];
            for (int j = st1; j < en1; ++j) {
                float4 fr = frac_s[j];
                float w = (ox ? fr.x : 1.f - fr.x) * (oy ? fr.y : 1.f - fr.y) * (1.f - fr.z);
                float4 f0 = feat_s[(size_t)j * 2 + 0];
                float4 f1 = feat_s[(size_t)j * 2 + 1];
                a0.x += w * f0.x; a0.y += w * f0.y; a0.z += w * f0.z; a0.w += w * f0.w;
                a1.x += w * f1.x; a1.y += w * f1.y; a1.z += w * f1.z; a1.w += w * f1.w;
            }
        }
    }
    float4* gp = reinterpret_cast<float4*>(grid + (size_t)n * DFEAT);
    gp[0] = a0;
    gp[1] = a1;
}

// ---------------- G2P over SORTED points: L2-local grid reads ----------------
__global__ __launch_bounds__(256) void g2p_sorted_kernel(
    const float4* __restrict__ frac_s,
    const int* __restrict__ orig_s,
    const float* __restrict__ grid,
    float* __restrict__ out)
{
    int j = blockIdx.x * blockDim.x + threadIdx.x;
    if (j >= NPTS) return;
    float4 fr = frac_s[j];
    int c = __float_as_int(fr.w);
    int bx = c >> 14, by = (c >> 7) & GMASK, bz = c & GMASK;

    float wx[2] = {1.0f - fr.x, fr.x};
    float wy[2] = {1.0f - fr.y, fr.y};
    float wz[2] = {1.0f - fr.z, fr.z};

    float4 acc0 = {0.f, 0.f, 0.f, 0.f};
    float4 acc1 = {0.f, 0.f, 0.f, 0.f};
#pragma unroll
    for (int o = 0; o < 8; ++o) {
        int ox = (o >> 2) & 1, oy = (o >> 1) & 1, oz = o & 1;
        float w = wx[ox] * wy[oy] * wz[oz];
        int cx = (bx + ox) & GMASK;
        int cy = (by + oy) & GMASK;
        int cz = (bz + oz) & GMASK;
        int hid = (cx << 14) | (cy << 7) | cz;
        const float4* g = reinterpret_cast<const float4*>(grid + (size_t)hid * DFEAT);
        float4 g0 = g[0];
        float4 g1 = g[1];
        acc0.x += w * g0.x; acc0.y += w * g0.y; acc0.z += w * g0.z; acc0.w += w * g0.w;
        acc1.x += w * g1.x; acc1.y += w * g1.y; acc1.z += w * g1.z; acc1.w += w * g1.w;
    }
    int orig = orig_s[j];
    float4* op = reinterpret_cast<float4*>(out + (size_t)orig * DFEAT);
    op[0] = acc0;
    op[1] = acc1;
}

// ---------------- fallback path kernels (ws too small) ----------------
__global__ __launch_bounds__(256) void p2g_atomic_kernel(
    const float* __restrict__ pos,
    const float* __restrict__ feat,
    float* __restrict__ grid)
{
    int n = blockIdx.x * blockDim.x + threadIdx.x;
    if (n >= NPTS) return;
    float px = pos[n * 3 + 0] * INV_CELL;
    float py = pos[n * 3 + 1] * INV_CELL;
    float pz = pos[n * 3 + 2] * INV_CELL;
    int bx = (int)floorf(px), by = (int)floorf(py), bz = (int)floorf(pz);
    float fx = px - (float)bx, fy = py - (float)by, fz = pz - (float)bz;
    const float4* fp = reinterpret_cast<const float4*>(feat + (size_t)n * DFEAT);
    float4 f0 = fp[0];
    float4 f1 = fp[1];
    float f[8] = {f0.x, f0.y, f0.z, f0.w, f1.x, f1.y, f1.z, f1.w};
    float wx[2] = {1.0f - fx, fx};
    float wy[2] = {1.0f - fy, fy};
    float wz[2] = {1.0f - fz, fz};
#pragma unroll
    for (int o = 0; o < 8; ++o) {
        int ox = (o >> 2) & 1, oy = (o >> 1) & 1, oz = o & 1;
        float w = wx[ox] * wy[oy] * wz[oz];
        int cx = (bx + ox) & GMASK, cy = (by + oy) & GMASK, cz = (bz + oz) & GMASK;
        int hid = (cx << 14) | (cy << 7) | cz;
        float* g = grid + (size_t)hid * DFEAT;
#pragma unroll
        for (int d = 0; d < DFEAT; ++d) atomicAdd(g + d, w * f[d]);
    }
}

__global__ __launch_bounds__(256) void g2p_kernel(
    const float* __restrict__ pos,
    const float* __restrict__ grid,
    float* __restrict__ out)
{
    int n = blockIdx.x * blockDim.x + threadIdx.x;
    if (n >= NPTS) return;
    float px = pos[n * 3 + 0] * INV_CELL;
    float py = pos[n * 3 + 1] * INV_CELL;
    float pz = pos[n * 3 + 2] * INV_CELL;
    int bx = (int)floorf(px), by = (int)floorf(py), bz = (int)floorf(pz);
    float fx = px - (float)bx, fy = py - (float)by, fz = pz - (float)bz;
    float wx[2] = {1.0f - fx, fx};
    float wy[2] = {1.0f - fy, fy};
    float wz[2] = {1.0f - fz, fz};
    float4 acc0 = {0.f, 0.f, 0.f, 0.f};
    float4 acc1 = {0.f, 0.f, 0.f, 0.f};
#pragma unroll
    for (int o = 0; o < 8; ++o) {
        int ox = (o >> 2) & 1, oy = (o >> 1) & 1, oz = o & 1;
        float w = wx[ox] * wy[oy] * wz[oz];
        int cx = (bx + ox) & GMASK;
        int cy = (by + oy) & GMASK;
        int cz = (bz + oz) & GMASK;
        int hid = (cx << 14) | (cy << 7) | cz;
        const float4* g = reinterpret_cast<const float4*>(grid + (size_t)hid * DFEAT);
        float4 g0 = g[0];
        float4 g1 = g[1];
        acc0.x += w * g0.x; acc0.y += w * g0.y; acc0.z += w * g0.z; acc0.w += w * g0.w;
        acc1.x += w * g1.x; acc1.y += w * g1.y; acc1.z += w * g1.z; acc1.w += w * g1.w;
    }
    float4* op = reinterpret_cast<float4*>(out + (size_t)n * DFEAT);
    op[0] = acc0;
    op[1] = acc1;
}

extern "C" void kernel_launch(void* const* d_in, const int* in_sizes, int n_in,
                              void* d_out, int out_size, void* d_ws, size_t ws_size,
                              hipStream_t stream) {
    const float* pos  = (const float*)d_in[0];   // [N,3] f32
    const float* feat = (const float*)d_in[1];   // [N,8] f32
    float* out = (float*)d_out;                  // [N,8] f32

    // workspace layout
    char* ws = (char*)d_ws;
    size_t grid_bytes    = (size_t)NUM_CELLS * DFEAT * sizeof(float);  // 64 MiB
    size_t offsets_bytes = (size_t)NUM_CELLS * sizeof(int);            // 8 MiB
    size_t frac_bytes    = (size_t)NPTS * sizeof(float4);              // 16 MB
    size_t feats_bytes   = (size_t)NPTS * 2 * sizeof(float4);          // 32 MB
    size_t orig_bytes    = (size_t)NPTS * sizeof(int);                 // 4 MB
    size_t partial_bytes = (size_t)NSCAN_BLOCKS * sizeof(int);         // 4 KiB

    float* grid     = (float*)ws;
    int* offsets    = (int*)(ws + grid_bytes);
    float4* frac_s  = (float4*)(ws + grid_bytes + offsets_bytes);
    float4* feat_s  = (float4*)(ws + grid_bytes + offsets_bytes + frac_bytes);
    int* orig_s     = (int*)(ws + grid_bytes + offsets_bytes + frac_bytes + feats_bytes);
    int* partial    = (int*)(ws + grid_bytes + offsets_bytes + frac_bytes + feats_bytes + orig_bytes);
    size_t needed = grid_bytes + offsets_bytes + frac_bytes + feats_bytes + orig_bytes + partial_bytes;

    int block = 256;
    int nblk_pts = (NPTS + block - 1) / block;
    int nblk_cells = NUM_CELLS / block;   // 8192

    if (ws_size >= needed) {
        // fast path: counting-sort (fused reorder) + node gather + sorted g2p
        hipMemsetAsync(offsets, 0, offsets_bytes, stream);
        hist_kernel<<<nblk_pts, block, 0, stream>>>(pos, offsets);
        scan_a<<<NSCAN_BLOCKS, SCAN_BLK, 0, stream>>>(offsets, partial);
        scan_b<<<1, NSCAN_BLOCKS, 0, stream>>>(partial);
        scan_c<<<nblk_cells, block, 0, stream>>>(offsets, partial);
        scatter_kernel<<<nblk_pts, block, 0, stream>>>(pos, feat, offsets, frac_s, feat_s, orig_s);
        node_gather_kernel<<<nblk_cells, block, 0, stream>>>(offsets, frac_s, feat_s, grid);
        g2p_sorted_kernel<<<nblk_pts, block, 0, stream>>>(frac_s, orig_s, grid, out);
    } else {
        // fallback: atomic scatter
        hipMemsetAsync(grid, 0, grid_bytes, stream);
        p2g_atomic_kernel<<<nblk_pts, block, 0, stream>>>(pos, feat, grid);
        g2p_kernel<<<nblk_pts, block, 0, stream>>>(pos, grid, out);
    }
}

// Round 8
// 262.714 us; speedup vs baseline: 12.9690x; 1.1771x over previous
//
#include <hip/hip_runtime.h>
#include <hip/hip_fp16.h>

#define GRIDSZ 128
#define GMASK 127
#define NUM_CELLS (GRIDSZ * GRIDSZ * GRIDSZ)   // 2,097,152
#define DFEAT 8
#define NPTS 1000000
#define INV_CELL 128.0f

#define SCAN_BLK 256
#define SCAN_ELEMS 8
#define SCAN_TILE 2048
#define SCAN_SHIFT 11
#define NSCAN_BLOCKS (NUM_CELLS / SCAN_TILE)    // 1024

// fp16 pack/unpack helpers
__device__ inline unsigned pack2h(float a, float b) {
    __half2 h = __floats2half2_rn(a, b);
    union { __half2 h; unsigned u; } cvt; cvt.h = h; return cvt.u;
}
__device__ inline float2 unpack2h(unsigned u) {
    union { unsigned u; __half2 h; } cvt; cvt.u = u;
    return __half22float2(cvt.h);
}

// cumulative offset = per-tile scanned value + tile base
__device__ inline int cum(const int* __restrict__ off, const int* __restrict__ partial, int c) {
    return off[c] + partial[c >> SCAN_SHIFT];
}

// ---------------- histogram: count points per cell ----------------
__global__ __launch_bounds__(256) void hist_kernel(
    const float* __restrict__ pos,
    int* __restrict__ counts)
{
    int n = blockIdx.x * blockDim.x + threadIdx.x;
    if (n >= NPTS) return;
    float px = pos[n * 3 + 0] * INV_CELL;
    float py = pos[n * 3 + 1] * INV_CELL;
    float pz = pos[n * 3 + 2] * INV_CELL;
    int bx = (int)floorf(px), by = (int)floorf(py), bz = (int)floorf(pz);
    int h = ((bx & GMASK) << 14) | ((by & GMASK) << 7) | (bz & GMASK);
    atomicAdd(&counts[h], 1);
}

// ---------------- scan: per-tile exclusive prefix IN PLACE + tile totals --------------
__global__ __launch_bounds__(SCAN_BLK) void scan_a(
    int* __restrict__ data,
    int* __restrict__ partial)
{
    __shared__ int lds[SCAN_BLK];
    int t = threadIdx.x;
    int base = blockIdx.x * SCAN_TILE + t * SCAN_ELEMS;
    int v[SCAN_ELEMS];
    int s = 0;
#pragma unroll
    for (int i = 0; i < SCAN_ELEMS; ++i) { v[i] = data[base + i]; s += v[i]; }
    lds[t] = s;
    __syncthreads();
    int incl = s;
    for (int off = 1; off < SCAN_BLK; off <<= 1) {
        int tmp = (t >= off) ? lds[t - off] : 0;
        __syncthreads();
        incl += tmp;
        lds[t] = incl;
        __syncthreads();
    }
    int excl = incl - s;
#pragma unroll
    for (int i = 0; i < SCAN_ELEMS; ++i) { data[base + i] = excl; excl += v[i]; }
    if (t == SCAN_BLK - 1) partial[blockIdx.x] = incl;
}

__global__ __launch_bounds__(1024) void scan_b(int* __restrict__ partial)
{
    __shared__ int lds[NSCAN_BLOCKS];
    int t = threadIdx.x;
    int p = partial[t];
    lds[t] = p;
    __syncthreads();
    int incl = p;
    for (int off = 1; off < NSCAN_BLOCKS; off <<= 1) {
        int tmp = (t >= off) ? lds[t - off] : 0;
        __syncthreads();
        incl += tmp;
        lds[t] = incl;
        __syncthreads();
    }
    partial[t] = incl - p;   // exclusive tile bases
}

// ---------------- scatter+reorder into packed 32-B records ----------------
// rec[2j]   = 8 x fp16 features
// rec[2j+1] = { fxq|fyq<<16, fzq, cell, orig }
// offsets stays per-tile-scanned; end(c) = offsets[c] + partial[c>>11] after scatter.
__global__ __launch_bounds__(256) void scatter_kernel(
    const float* __restrict__ pos,
    const float* __restrict__ feat,
    int* __restrict__ offsets,
    const int* __restrict__ partial,
    uint4* __restrict__ rec)
{
    int n = blockIdx.x * blockDim.x + threadIdx.x;
    if (n >= NPTS) return;
    float px = pos[n * 3 + 0] * INV_CELL;
    float py = pos[n * 3 + 1] * INV_CELL;
    float pz = pos[n * 3 + 2] * INV_CELL;
    int bx = (int)floorf(px), by = (int)floorf(py), bz = (int)floorf(pz);
    float fx = px - (float)bx, fy = py - (float)by, fz = pz - (float)bz;
    int c = ((bx & GMASK) << 14) | ((by & GMASK) << 7) | (bz & GMASK);
    int slot = atomicAdd(&offsets[c], 1) + partial[c >> SCAN_SHIFT];

    const float4* fp = reinterpret_cast<const float4*>(feat + (size_t)n * DFEAT);
    float4 f0 = fp[0];
    float4 f1 = fp[1];

    uint4 A, B;
    A.x = pack2h(f0.x, f0.y);
    A.y = pack2h(f0.z, f0.w);
    A.z = pack2h(f1.x, f1.y);
    A.w = pack2h(f1.z, f1.w);
    unsigned qx = min((unsigned)(fx * 65536.0f), 65535u);
    unsigned qy = min((unsigned)(fy * 65536.0f), 65535u);
    unsigned qz = min((unsigned)(fz * 65536.0f), 65535u);
    B.x = qx | (qy << 16);
    B.y = qz;
    B.z = (unsigned)c;
    B.w = (unsigned)n;

    uint4* dst = rec + (size_t)slot * 2;
    dst[0] = A;
    dst[1] = B;
}

// ---------------- node gather: P2G without atomics, z-merged ranges, fp16 grid ------
__global__ __launch_bounds__(256) void node_gather_kernel(
    const int* __restrict__ offsets_end,
    const int* __restrict__ partial,
    const uint4* __restrict__ rec,
    uint4* __restrict__ gridh)          // [NUM_CELLS] 8 x fp16
{
    int n = blockIdx.x * blockDim.x + threadIdx.x;   // exactly NUM_CELLS threads
    int nz = n & GMASK, ny = (n >> 7) & GMASK, nx = n >> 14;
    float4 a0 = {0.f, 0.f, 0.f, 0.f};
    float4 a1 = {0.f, 0.f, 0.f, 0.f};
#pragma unroll
    for (int oxy = 0; oxy < 4; ++oxy) {
        int ox = oxy >> 1, oy = oxy & 1;
        int bx = (nx - ox) & GMASK, by = (ny - oy) & GMASK;
        int cbase = (bx << 14) | (by << 7);
        int c1 = cbase | nz;
        if (nz > 0) {
            int c0 = c1 - 1;
            int st0 = (c0 == 0) ? 0 : cum(offsets_end, partial, c0 - 1);
            int en0 = cum(offsets_end, partial, c0);
            int en1 = cum(offsets_end, partial, c1);
            for (int j = st0; j < en1; ++j) {
                const uint4* rp = rec + (size_t)j * 2;
                uint4 A = rp[0];
                uint4 B = rp[1];
                float fx = (float)(B.x & 0xffffu) * (1.f / 65536.f);
                float fy = (float)(B.x >> 16) * (1.f / 65536.f);
                float fz = (float)(B.y & 0xffffu) * (1.f / 65536.f);
                float wz = (j < en0) ? fz : 1.f - fz;
                float w = (ox ? fx : 1.f - fx) * (oy ? fy : 1.f - fy) * wz;
                float2 p;
                p = unpack2h(A.x); a0.x += w * p.x; a0.y += w * p.y;
                p = unpack2h(A.y); a0.z += w * p.x; a0.w += w * p.y;
                p = unpack2h(A.z); a1.x += w * p.x; a1.y += w * p.y;
                p = unpack2h(A.w); a1.z += w * p.x; a1.w += w * p.y;
            }
        } else {
            int c0 = cbase | 127;
            int st0 = cum(offsets_end, partial, c0 - 1);
            int en0 = cum(offsets_end, partial, c0);
            for (int j = st0; j < en0; ++j) {
                const uint4* rp = rec + (size_t)j * 2;
                uint4 A = rp[0];
                uint4 B = rp[1];
                float fx = (float)(B.x & 0xffffu) * (1.f / 65536.f);
                float fy = (float)(B.x >> 16) * (1.f / 65536.f);
                float fz = (float)(B.y & 0xffffu) * (1.f / 65536.f);
                float w = (ox ? fx : 1.f - fx) * (oy ? fy : 1.f - fy) * fz;
                float2 p;
                p = unpack2h(A.x); a0.x += w * p.x; a0.y += w * p.y;
                p = unpack2h(A.y); a0.z += w * p.x; a0.w += w * p.y;
                p = unpack2h(A.z); a1.x += w * p.x; a1.y += w * p.y;
                p = unpack2h(A.w); a1.z += w * p.x; a1.w += w * p.y;
            }
            int st1 = (c1 == 0) ? 0 : cum(offsets_end, partial, c1 - 1);
            int en1 = cum(offsets_end, partial, c1);
            for (int j = st1; j < en1; ++j) {
                const uint4* rp = rec + (size_t)j * 2;
                uint4 A = rp[0];
                uint4 B = rp[1];
                float fx = (float)(B.x & 0xffffu) * (1.f / 65536.f);
                float fy = (float)(B.x >> 16) * (1.f / 65536.f);
                float fz = (float)(B.y & 0xffffu) * (1.f / 65536.f);
                float w = (ox ? fx : 1.f - fx) * (oy ? fy : 1.f - fy) * (1.f - fz);
                float2 p;
                p = unpack2h(A.x); a0.x += w * p.x; a0.y += w * p.y;
                p = unpack2h(A.y); a0.z += w * p.x; a0.w += w * p.y;
                p = unpack2h(A.z); a1.x += w * p.x; a1.y += w * p.y;
                p = unpack2h(A.w); a1.z += w * p.x; a1.w += w * p.y;
            }
        }
    }
    uint4 g;
    g.x = pack2h(a0.x, a0.y);
    g.y = pack2h(a0.z, a0.w);
    g.z = pack2h(a1.x, a1.y);
    g.w = pack2h(a1.z, a1.w);
    gridh[n] = g;
}

// ---------------- G2P over SORTED points: fp16 grid, L2-local reads ----------------
__global__ __launch_bounds__(256) void g2p_sorted_kernel(
    const uint4* __restrict__ rec,
    const uint4* __restrict__ gridh,
    float* __restrict__ out)
{
    int j = blockIdx.x * blockDim.x + threadIdx.x;
    if (j >= NPTS) return;
    uint4 B = rec[(size_t)j * 2 + 1];
    float fx = (float)(B.x & 0xffffu) * (1.f / 65536.f);
    float fy = (float)(B.x >> 16) * (1.f / 65536.f);
    float fz = (float)(B.y & 0xffffu) * (1.f / 65536.f);
    int c = (int)B.z;
    int orig = (int)B.w;
    int bx = c >> 14, by = (c >> 7) & GMASK, bz = c & GMASK;

    float wx[2] = {1.0f - fx, fx};
    float wy[2] = {1.0f - fy, fy};
    float wz[2] = {1.0f - fz, fz};

    float4 acc0 = {0.f, 0.f, 0.f, 0.f};
    float4 acc1 = {0.f, 0.f, 0.f, 0.f};
#pragma unroll
    for (int o = 0; o < 8; ++o) {
        int ox = (o >> 2) & 1, oy = (o >> 1) & 1, oz = o & 1;
        float w = wx[ox] * wy[oy] * wz[oz];
        int cx = (bx + ox) & GMASK;
        int cy = (by + oy) & GMASK;
        int cz = (bz + oz) & GMASK;
        int hid = (cx << 14) | (cy << 7) | cz;
        uint4 g = gridh[hid];
        float2 p;
        p = unpack2h(g.x); acc0.x += w * p.x; acc0.y += w * p.y;
        p = unpack2h(g.y); acc0.z += w * p.x; acc0.w += w * p.y;
        p = unpack2h(g.z); acc1.x += w * p.x; acc1.y += w * p.y;
        p = unpack2h(g.w); acc1.z += w * p.x; acc1.w += w * p.y;
    }
    float4* op = reinterpret_cast<float4*>(out + (size_t)orig * DFEAT);
    op[0] = acc0;
    op[1] = acc1;
}

// ---------------- fallback path kernels (ws too small) ----------------
__global__ __launch_bounds__(256) void p2g_atomic_kernel(
    const float* __restrict__ pos,
    const float* __restrict__ feat,
    float* __restrict__ grid)
{
    int n = blockIdx.x * blockDim.x + threadIdx.x;
    if (n >= NPTS) return;
    float px = pos[n * 3 + 0] * INV_CELL;
    float py = pos[n * 3 + 1] * INV_CELL;
    float pz = pos[n * 3 + 2] * INV_CELL;
    int bx = (int)floorf(px), by = (int)floorf(py), bz = (int)floorf(pz);
    float fx = px - (float)bx, fy = py - (float)by, fz = pz - (float)bz;
    const float4* fp = reinterpret_cast<const float4*>(feat + (size_t)n * DFEAT);
    float4 f0 = fp[0];
    float4 f1 = fp[1];
    float f[8] = {f0.x, f0.y, f0.z, f0.w, f1.x, f1.y, f1.z, f1.w};
    float wx[2] = {1.0f - fx, fx};
    float wy[2] = {1.0f - fy, fy};
    float wz[2] = {1.0f - fz, fz};
#pragma unroll
    for (int o = 0; o < 8; ++o) {
        int ox = (o >> 2) & 1, oy = (o >> 1) & 1, oz = o & 1;
        float w = wx[ox] * wy[oy] * wz[oz];
        int cx = (bx + ox) & GMASK, cy = (by + oy) & GMASK, cz = (bz + oz) & GMASK;
        int hid = (cx << 14) | (cy << 7) | cz;
        float* g = grid + (size_t)hid * DFEAT;
#pragma unroll
        for (int d = 0; d < DFEAT; ++d) atomicAdd(g + d, w * f[d]);
    }
}

__global__ __launch_bounds__(256) void g2p_kernel(
    const float* __restrict__ pos,
    const float* __restrict__ grid,
    float* __restrict__ out)
{
    int n = blockIdx.x * blockDim.x + threadIdx.x;
    if (n >= NPTS) return;
    float px = pos[n * 3 + 0] * INV_CELL;
    float py = pos[n * 3 + 1] * INV_CELL;
    float pz = pos[n * 3 + 2] * INV_CELL;
    int bx = (int)floorf(px), by = (int)floorf(py), bz = (int)floorf(pz);
    float fx = px - (float)bx, fy = py - (float)by, fz = pz - (float)bz;
    float wx[2] = {1.0f - fx, fx};
    float wy[2] = {1.0f - fy, fy};
    float wz[2] = {1.0f - fz, fz};
    float4 acc0 = {0.f, 0.f, 0.f, 0.f};
    float4 acc1 = {0.f, 0.f, 0.f, 0.f};
#pragma unroll
    for (int o = 0; o < 8; ++o) {
        int ox = (o >> 2) & 1, oy = (o >> 1) & 1, oz = o & 1;
        float w = wx[ox] * wy[oy] * wz[oz];
        int cx = (bx + ox) & GMASK;
        int cy = (by + oy) & GMASK;
        int cz = (bz + oz) & GMASK;
        int hid = (cx << 14) | (cy << 7) | cz;
        const float4* g = reinterpret_cast<const float4*>(grid + (size_t)hid * DFEAT);
        float4 g0 = g[0];
        float4 g1 = g[1];
        acc0.x += w * g0.x; acc0.y += w * g0.y; acc0.z += w * g0.z; acc0.w += w * g0.w;
        acc1.x += w * g1.x; acc1.y += w * g1.y; acc1.z += w * g1.z; acc1.w += w * g1.w;
    }
    float4* op = reinterpret_cast<float4*>(out + (size_t)n * DFEAT);
    op[0] = acc0;
    op[1] = acc1;
}

extern "C" void kernel_launch(void* const* d_in, const int* in_sizes, int n_in,
                              void* d_out, int out_size, void* d_ws, size_t ws_size,
                              hipStream_t stream) {
    const float* pos  = (const float*)d_in[0];   // [N,3] f32
    const float* feat = (const float*)d_in[1];   // [N,8] f32
    float* out = (float*)d_out;                  // [N,8] f32

    // fast-path workspace layout
    char* ws = (char*)d_ws;
    size_t gridh_bytes   = (size_t)NUM_CELLS * sizeof(uint4);          // 32 MiB
    size_t offsets_bytes = (size_t)NUM_CELLS * sizeof(int);            // 8 MiB
    size_t rec_bytes     = (size_t)NPTS * 2 * sizeof(uint4);           // 32 MB
    size_t partial_bytes = (size_t)NSCAN_BLOCKS * sizeof(int);         // 4 KiB

    uint4* gridh  = (uint4*)ws;
    int* offsets  = (int*)(ws + gridh_bytes);
    uint4* rec    = (uint4*)(ws + gridh_bytes + offsets_bytes);
    int* partial  = (int*)(ws + gridh_bytes + offsets_bytes + rec_bytes);
    size_t needed = gridh_bytes + offsets_bytes + rec_bytes + partial_bytes;

    int block = 256;
    int nblk_pts = (NPTS + block - 1) / block;
    int nblk_cells = NUM_CELLS / block;   // 8192

    if (ws_size >= needed) {
        // fast path: counting-sort into packed records + node gather + sorted g2p
        hipMemsetAsync(offsets, 0, offsets_bytes, stream);
        hist_kernel<<<nblk_pts, block, 0, stream>>>(pos, offsets);
        scan_a<<<NSCAN_BLOCKS, SCAN_BLK, 0, stream>>>(offsets, partial);
        scan_b<<<1, NSCAN_BLOCKS, 0, stream>>>(partial);
        scatter_kernel<<<nblk_pts, block, 0, stream>>>(pos, feat, offsets, partial, rec);
        node_gather_kernel<<<nblk_cells, block, 0, stream>>>(offsets, partial, rec, gridh);
        g2p_sorted_kernel<<<nblk_pts, block, 0, stream>>>(rec, gridh, out);
    } else {
        // fallback: atomic scatter with f32 grid
        float* grid = (float*)ws;
        hipMemsetAsync(grid, 0, (size_t)NUM_CELLS * DFEAT * sizeof(float), stream);
        p2g_atomic_kernel<<<nblk_pts, block, 0, stream>>>(pos, feat, grid);
        g2p_kernel<<<nblk_pts, block, 0, stream>>>(pos, grid, out);
    }
}